// Round 7
// baseline (346.431 us; speedup 1.0000x reference)
//
#include <hip/hip_runtime.h>
#include <hip/hip_bf16.h>

// fp32 inputs (confirmed r2). Internal pipeline bf16 MFMA.
// Gen identity: w = exp2(max(e,0.2e)) = max(A_i*B_j, C_i*D_j).
// r19b = resubmit of r19 (round-6 bench was an infra failure: "container failed
//   twice", no measurement). Kernel audited: no in-loop barriers (no deadlock),
//   all tail overreads land in mapped workspace (WT/expD/pkm), no capture
//   violations. Same predictions/falsifier as r19.
// r19 = r18 barrier-free direct-load attn, spill-fixed (r18 failure = 183MB
//   scratch WRITE: live set 132+ regs > 128 cap):
//   - denominator via VALU adds on masked w (same summands as P@ones MFMA,
//     different order) + shfl_xor quad-reduce: frees accd(8)+onef(4) regs,
//     MFMA cluster 10->8.
//   - pBD single-deep (refill kb+1 before MFMA cluster; MFMA+gen covers L2
//     latency): frees 16 regs.
//   - pv stays 2-deep (parity slots, refill kb+2 after MFMA).
//   Live set ~112 <= 128 -> no spill at 4 waves/SIMD, launch_bounds(512,4).
//   All loads unconditional (tail overreads mapped workspace; r18-proven).
// Mask layout: byte pk[i*512 + g*32 + kb] bits r for j = kb*128 + (g>>2)*32 + (g&3)*8 + r.

typedef unsigned short ushort_t;
typedef __attribute__((ext_vector_type(8))) short bf16x8;
typedef __attribute__((ext_vector_type(4))) float f32x4;

#define LOG2E 1.4426950408889634f

__device__ __forceinline__ ushort_t f2bf(float x) {
    unsigned u = __builtin_bit_cast(unsigned, x);
    u += 0x7FFFu + ((u >> 16) & 1u);   // RNE
    return (ushort_t)(u >> 16);
}

// ---------------- kernel 1: WT[c][k] = W[k][c], 512x512, fp32 -> bf16 ----------------
__global__ __launch_bounds__(256) void transpose_w(const float* __restrict__ W,
                                                   ushort_t* __restrict__ WT) {
    __shared__ ushort_t t[32][33];
    int bx = blockIdx.x & 15, by = blockIdx.x >> 4;
    int tx = threadIdx.x & 31, ty = threadIdx.x >> 5;
#pragma unroll
    for (int i = 0; i < 32; i += 8)
        t[ty + i][tx] = f2bf(W[(by * 32 + ty + i) * 512 + bx * 32 + tx]);
    __syncthreads();
#pragma unroll
    for (int i = 0; i < 32; i += 8)
        WT[(bx * 32 + ty + i) * 512 + by * 32 + tx] = t[tx][ty + i];
}

// -------- kernel 2 (fused): blocks 0-511 = gemm (r8 proven body); 512-1535 = pack ----
__global__ __launch_bounds__(256, 4) void gemm_pack(const ushort_t* __restrict__ WT,
                                                    const float* __restrict__ h,
                                                    const float* __restrict__ a,
                                                    ushort_t* __restrict__ WhT,
                                                    float* __restrict__ expA,
                                                    float* __restrict__ expC,
                                                    float* __restrict__ expB,
                                                    float* __restrict__ expD,
                                                    const int* __restrict__ adj,
                                                    unsigned char* __restrict__ pk) {
    __shared__ __align__(16) ushort_t Al[2][64][72];
    __shared__ __align__(16) ushort_t Bl[2][64][72];
    __shared__ float asrc[64], adst[64];
    __shared__ float sred[2][4][64];
    int tid = threadIdx.x;
    if (blockIdx.x >= 512) {
        // ---------------- pack branch ----------------
        int pbid = blockIdx.x - 512;
        int wv = tid >> 6, lane = tid & 63;
        int row = pbid * 4 + wv;
        const int* ap = adj + (unsigned)row * 4096 + lane;
        unsigned char* pp = pk + (unsigned)row * 512;
        int g = lane;                                 // lanes 0..15 write
        int sv = ((g >> 2) & 1) * 4 + (g & 3);
        int cpar = g >> 3;
#pragma unroll 2
        for (int t = 0; t < 8; t++) {
            unsigned long long m[8];
#pragma unroll
            for (int c8 = 0; c8 < 8; c8++)
                m[c8] = __ballot(ap[(t * 8 + c8) * 64] > 0);
            if (lane < 16) {
                unsigned w = 0;
#pragma unroll
                for (int kq = 0; kq < 4; kq++) {
                    unsigned b = (unsigned)(m[2 * kq + cpar] >> (8 * sv)) & 0xFFu;
                    w |= b << (8 * kq);
                }
                *(unsigned*)(pp + g * 32 + t * 4) = w;
            }
        }
        return;
    }
    // ---------------- gemm branch (r8/r12 proven) ----------------
    int wave = tid >> 6, lane = tid & 63, quad = lane >> 4, nn = lane & 15;
    int mb = blockIdx.x & 7, nb = blockIdx.x >> 3;
    if (tid < 64) {
        asrc[tid] = a[tid] * LOG2E;
        adst[tid] = a[64 + tid] * LOG2E;
    }
    int r = tid >> 2, s0 = tid & 3;
    const ushort_t* Ag = WT + (unsigned)((mb * 64 + r) * 512 + s0 * 8);
    const float* Bg = h + (unsigned)((nb * 64 + r) * 512 + s0 * 8);
    bf16x8 pA0 = *(const bf16x8*)(Ag);
    bf16x8 pA1 = *(const bf16x8*)(Ag + 32);
    float4 pb0 = *(const float4*)(Bg);
    float4 pb1 = *(const float4*)(Bg + 4);
    float4 pb2 = *(const float4*)(Bg + 32);
    float4 pb3 = *(const float4*)(Bg + 36);
    f32x4 acc[4] = {};
#pragma unroll 2
    for (int t = 0; t < 8; t++) {
        int cb = t & 1;
        *(bf16x8*)&Al[cb][r][s0 * 8] = pA0;
        *(bf16x8*)&Al[cb][r][s0 * 8 + 32] = pA1;
        bf16x8 bv;
        bv[0] = (short)f2bf(pb0.x); bv[1] = (short)f2bf(pb0.y);
        bv[2] = (short)f2bf(pb0.z); bv[3] = (short)f2bf(pb0.w);
        bv[4] = (short)f2bf(pb1.x); bv[5] = (short)f2bf(pb1.y);
        bv[6] = (short)f2bf(pb1.z); bv[7] = (short)f2bf(pb1.w);
        *(bf16x8*)&Bl[cb][r][s0 * 8] = bv;
        bv[0] = (short)f2bf(pb2.x); bv[1] = (short)f2bf(pb2.y);
        bv[2] = (short)f2bf(pb2.z); bv[3] = (short)f2bf(pb2.w);
        bv[4] = (short)f2bf(pb3.x); bv[5] = (short)f2bf(pb3.y);
        bv[6] = (short)f2bf(pb3.z); bv[7] = (short)f2bf(pb3.w);
        *(bf16x8*)&Bl[cb][r][s0 * 8 + 32] = bv;
        if (t < 7) {
            int ko = (t + 1) * 64;
            pA0 = *(const bf16x8*)(Ag + ko);
            pA1 = *(const bf16x8*)(Ag + ko + 32);
            pb0 = *(const float4*)(Bg + ko);
            pb1 = *(const float4*)(Bg + ko + 4);
            pb2 = *(const float4*)(Bg + ko + 32);
            pb3 = *(const float4*)(Bg + ko + 36);
        }
        if (t > 0) {
            int pb = cb ^ 1;
            bf16x8 af0 = *(const bf16x8*)&Al[pb][wave * 16 + nn][quad * 8];
            bf16x8 af1 = *(const bf16x8*)&Al[pb][wave * 16 + nn][32 + quad * 8];
#pragma unroll
            for (int nt = 0; nt < 4; nt++) {
                bf16x8 b0 = *(const bf16x8*)&Bl[pb][nt * 16 + nn][quad * 8];
                bf16x8 b1 = *(const bf16x8*)&Bl[pb][nt * 16 + nn][32 + quad * 8];
                acc[nt] = __builtin_amdgcn_mfma_f32_16x16x32_bf16(af0, b0, acc[nt], 0, 0, 0);
                acc[nt] = __builtin_amdgcn_mfma_f32_16x16x32_bf16(af1, b1, acc[nt], 0, 0, 0);
            }
        }
        __syncthreads();
    }
    {
        bf16x8 af0 = *(const bf16x8*)&Al[1][wave * 16 + nn][quad * 8];
        bf16x8 af1 = *(const bf16x8*)&Al[1][wave * 16 + nn][32 + quad * 8];
#pragma unroll
        for (int nt = 0; nt < 4; nt++) {
            bf16x8 b0 = *(const bf16x8*)&Bl[1][nt * 16 + nn][quad * 8];
            bf16x8 b1 = *(const bf16x8*)&Bl[1][nt * 16 + nn][32 + quad * 8];
            acc[nt] = __builtin_amdgcn_mfma_f32_16x16x32_bf16(af0, b0, acc[nt], 0, 0, 0);
            acc[nt] = __builtin_amdgcn_mfma_f32_16x16x32_bf16(af1, b1, acc[nt], 0, 0, 0);
        }
    }
    int row0 = mb * 64 + wave * 16 + quad * 4;
    int col0 = nb * 64 + nn;
    int f0i = wave * 16 + quad * 4;
#pragma unroll
    for (int nt = 0; nt < 4; nt++) {
        float s = 0.f, d = 0.f;
#pragma unroll
        for (int rr = 0; rr < 4; rr++) {
            float v = acc[nt][rr];
            WhT[(unsigned)((row0 + rr) * 4096 + col0 + nt * 16)] = f2bf(v);
            s += v * asrc[f0i + rr];
            d += v * adst[f0i + rr];
        }
        s += __shfl_xor(s, 16); s += __shfl_xor(s, 32);
        d += __shfl_xor(d, 16); d += __shfl_xor(d, 32);
        if (quad == 0) { sred[0][wave][nt * 16 + nn] = s; sred[1][wave][nt * 16 + nn] = d; }
    }
    __syncthreads();
    if (tid < 64) {
        float s = sred[0][0][tid] + sred[0][1][tid] + sred[0][2][tid] + sred[0][3][tid];
        unsigned idx = mb * 4096 + nb * 64 + tid;
        expA[idx] = __builtin_amdgcn_exp2f(s);
        expC[idx] = __builtin_amdgcn_exp2f(0.2f * s);
    } else if (tid < 128) {
        int c = tid - 64;
        float d = sred[1][0][c] + sred[1][1][c] + sred[1][2][c] + sred[1][3][c];
        unsigned idx = mb * 4096 + nb * 64 + c;
        expB[idx] = __builtin_amdgcn_exp2f(d);
        expD[idx] = __builtin_amdgcn_exp2f(0.2f * d);
    }
}

// -------- kernel 3: fused attention, barrier-free, direct V loads, spill-free -------
// 512 blocks x 512 thr (512,4). wave=(whead, jq); thread gen = A-frags for rows nn
// and 16+nn over j = kb*128 + jq*32 + quad*8 + 0..7. 32 phases, NO in-loop barriers.
// Per phase kb: gen from pBD (tile kb, loaded last phase) + dn VALU accumulate ->
// refill pBD (kb+1) -> MFMA with pv parity slot (kb, loaded 2 phases ago) ->
// refill that slot (kb+2). Denominator via dn adds + shfl quad-reduce (no MFMA).

// gen one strip: produces AF (bf16x8 A-frag) and accumulates masked w sum into DN.
#define GEN_STRIP(AF, Ai, Ci, MC, DN, UU)                                             \
    {                                                                                 \
        unsigned w0, w1, w2, w3, w4, w5, w6, w7;                                      \
        float w;                                                                      \
        w = fmaxf((Ai) * Bv0.x, (Ci) * Dv0.x);                                        \
        w0 = __builtin_bit_cast(unsigned, w) & 0xFFFF0000u;                           \
        w0 &= (unsigned)__builtin_amdgcn_sbfe(MC, (UU) * 8 + 0, 1);                   \
        w = fmaxf((Ai) * Bv0.y, (Ci) * Dv0.y);                                        \
        w1 = __builtin_bit_cast(unsigned, w) & 0xFFFF0000u;                           \
        w1 &= (unsigned)__builtin_amdgcn_sbfe(MC, (UU) * 8 + 1, 1);                   \
        w = fmaxf((Ai) * Bv0.z, (Ci) * Dv0.z);                                        \
        w2 = __builtin_bit_cast(unsigned, w) & 0xFFFF0000u;                           \
        w2 &= (unsigned)__builtin_amdgcn_sbfe(MC, (UU) * 8 + 2, 1);                   \
        w = fmaxf((Ai) * Bv0.w, (Ci) * Dv0.w);                                        \
        w3 = __builtin_bit_cast(unsigned, w) & 0xFFFF0000u;                           \
        w3 &= (unsigned)__builtin_amdgcn_sbfe(MC, (UU) * 8 + 3, 1);                   \
        w = fmaxf((Ai) * Bv1.x, (Ci) * Dv1.x);                                        \
        w4 = __builtin_bit_cast(unsigned, w) & 0xFFFF0000u;                           \
        w4 &= (unsigned)__builtin_amdgcn_sbfe(MC, (UU) * 8 + 4, 1);                   \
        w = fmaxf((Ai) * Bv1.y, (Ci) * Dv1.y);                                        \
        w5 = __builtin_bit_cast(unsigned, w) & 0xFFFF0000u;                           \
        w5 &= (unsigned)__builtin_amdgcn_sbfe(MC, (UU) * 8 + 5, 1);                   \
        w = fmaxf((Ai) * Bv1.z, (Ci) * Dv1.z);                                        \
        w6 = __builtin_bit_cast(unsigned, w) & 0xFFFF0000u;                           \
        w6 &= (unsigned)__builtin_amdgcn_sbfe(MC, (UU) * 8 + 6, 1);                   \
        w = fmaxf((Ai) * Bv1.w, (Ci) * Dv1.w);                                        \
        w7 = __builtin_bit_cast(unsigned, w) & 0xFFFF0000u;                           \
        w7 &= (unsigned)__builtin_amdgcn_sbfe(MC, (UU) * 8 + 7, 1);                   \
        DN += ((__builtin_bit_cast(float, w0) + __builtin_bit_cast(float, w1))        \
             + (__builtin_bit_cast(float, w2) + __builtin_bit_cast(float, w3)))       \
            + ((__builtin_bit_cast(float, w4) + __builtin_bit_cast(float, w5))        \
             + (__builtin_bit_cast(float, w6) + __builtin_bit_cast(float, w7)));      \
        uint4 pq;                                                                     \
        pq.x = __builtin_amdgcn_perm(w1, w0, 0x07060302u);                            \
        pq.y = __builtin_amdgcn_perm(w3, w2, 0x07060302u);                            \
        pq.z = __builtin_amdgcn_perm(w5, w4, 0x07060302u);                            \
        pq.w = __builtin_amdgcn_perm(w7, w6, 0x07060302u);                            \
        AF = __builtin_bit_cast(bf16x8, pq);                                          \
    }

// Phase kb (UU = kb&3). Entry: Vg/Bp/Dp -> tile kb; pBDa holds kb; PV holds kb;
// other pv slot holds kb+1. Exit: pointers advanced one tile.
#define ATT_PHASE(UU, PV)                                                             \
    {                                                                                 \
        float4 Bv0 = pBDa[0], Bv1 = pBDa[1], Dv0 = pBDa[2], Dv1 = pBDa[3];            \
        bf16x8 af0, af1;                                                              \
        GEN_STRIP(af0, Ai0, Ci0, mcA, dn0, UU)                                        \
        GEN_STRIP(af1, Ai1, Ci1, mcB, dn1, UU)                                        \
        if (UU == 3) { mcA = mnA; mcB = mnB; }                                        \
        /* refill pBD with tile kb+1 (consumed next phase; MFMA covers latency) */    \
        pBDa[0] = *(const float4*)(Bp + 128);                                         \
        pBDa[1] = *(const float4*)(Bp + 132);                                         \
        pBDa[2] = *(const float4*)(Dp + 128);                                         \
        pBDa[3] = *(const float4*)(Dp + 132);                                         \
        if (UU == 0) {                                                                \
            mnA = *(const unsigned*)(mpA + 4);                                        \
            mnB = *(const unsigned*)(mpB + 4);                                        \
        }                                                                             \
        __builtin_amdgcn_s_setprio(1);                                                \
        acc[0][0] = __builtin_amdgcn_mfma_f32_16x16x32_bf16(af0, PV[0], acc[0][0], 0, 0, 0); \
        acc[1][0] = __builtin_amdgcn_mfma_f32_16x16x32_bf16(af1, PV[0], acc[1][0], 0, 0, 0); \
        acc[0][1] = __builtin_amdgcn_mfma_f32_16x16x32_bf16(af0, PV[1], acc[0][1], 0, 0, 0); \
        acc[1][1] = __builtin_amdgcn_mfma_f32_16x16x32_bf16(af1, PV[1], acc[1][1], 0, 0, 0); \
        acc[0][2] = __builtin_amdgcn_mfma_f32_16x16x32_bf16(af0, PV[2], acc[0][2], 0, 0, 0); \
        acc[1][2] = __builtin_amdgcn_mfma_f32_16x16x32_bf16(af1, PV[2], acc[1][2], 0, 0, 0); \
        acc[0][3] = __builtin_amdgcn_mfma_f32_16x16x32_bf16(af0, PV[3], acc[0][3], 0, 0, 0); \
        acc[1][3] = __builtin_amdgcn_mfma_f32_16x16x32_bf16(af1, PV[3], acc[1][3], 0, 0, 0); \
        __builtin_amdgcn_s_setprio(0);                                                \
        /* refill this pv parity slot with tile kb+2 */                               \
        PV[0] = *(const bf16x8*)(Vg + 256);                                           \
        PV[1] = *(const bf16x8*)(Vg + 256 + 65536);                                   \
        PV[2] = *(const bf16x8*)(Vg + 256 + 131072);                                  \
        PV[3] = *(const bf16x8*)(Vg + 256 + 196608);                                  \
        if (UU == 3) { mpA += 4; mpB += 4; }                                          \
        Vg += 128; Bp += 128; Dp += 128;                                              \
    }

__global__ __launch_bounds__(512, 4) void gat_attn(const unsigned char* __restrict__ pk,
                                                   const ushort_t* __restrict__ WhT,
                                                   const float* __restrict__ expA,
                                                   const float* __restrict__ expC,
                                                   const float* __restrict__ expB,
                                                   const float* __restrict__ expD,
                                                   float* __restrict__ out) {
    __shared__ __align__(16) float cmb[2][3][64][32];   // 49152 B, epilogue combine
    __shared__ float denomp[4][2][32];                  // 1024 B
    int tid = threadIdx.x;
    int wave = tid >> 6, lane = tid & 63, quad = lane >> 4, nn = lane & 15;
    int hb = blockIdx.x >> 7, ib = blockIdx.x & 127;
    int i0 = ib * 32;
    int whead = wave & 1, jq = wave >> 1;              // jq 0..3
    int g = jq * 4 + quad;
    int head = hb * 2 + whead;
    float Ai0 = expA[head * 4096 + i0 + nn];
    float Ci0 = expC[head * 4096 + i0 + nn];
    float Ai1 = expA[head * 4096 + i0 + 16 + nn];
    float Ci1 = expC[head * 4096 + i0 + 16 + nn];
    const unsigned char* mpA = pk + (unsigned)(i0 + nn) * 512 + g * 32;
    const unsigned char* mpB = mpA + 16 * 512;
    const float* Bp = expB + (unsigned)head * 4096 + jq * 32 + quad * 8;
    const float* Dp = expD + (unsigned)head * 4096 + jq * 32 + quad * 8;
    // V fragment base: row (hb*128 + whead*64 + nn), col jq*32 + quad*8; nt adds
    // nt*16 rows = nt*65536 ushorts; per phase the base advances 128 cols.
    const ushort_t* Vg = WhT + (unsigned)(hb * 128 + whead * 64 + nn) * 4096
                             + jq * 32 + quad * 8;
    f32x4 acc[2][4] = {};
    float dn0 = 0.f, dn1 = 0.f;
    bf16x8 pva[4], pvb[4];
    float4 pBDa[4];
    // prologue: pva = tile 0, pvb = tile 1, pBDa = tile 0
    pva[0] = *(const bf16x8*)(Vg);
    pva[1] = *(const bf16x8*)(Vg + 65536);
    pva[2] = *(const bf16x8*)(Vg + 131072);
    pva[3] = *(const bf16x8*)(Vg + 196608);
    pvb[0] = *(const bf16x8*)(Vg + 128);
    pvb[1] = *(const bf16x8*)(Vg + 128 + 65536);
    pvb[2] = *(const bf16x8*)(Vg + 128 + 131072);
    pvb[3] = *(const bf16x8*)(Vg + 128 + 196608);
    pBDa[0] = *(const float4*)(Bp);
    pBDa[1] = *(const float4*)(Bp + 4);
    pBDa[2] = *(const float4*)(Dp);
    pBDa[3] = *(const float4*)(Dp + 4);
    unsigned mcA = *(const unsigned*)(mpA);
    unsigned mcB = *(const unsigned*)(mpB);
    unsigned mnA = 0, mnB = 0;
    for (int t = 0; t < 8; t++) {
        ATT_PHASE(0, pva)
        ATT_PHASE(1, pvb)
        ATT_PHASE(2, pva)
        ATT_PHASE(3, pvb)
    }
    // denominator: quad-reduce the per-thread sums (rows nn and 16+nn)
    dn0 += __shfl_xor(dn0, 16); dn0 += __shfl_xor(dn0, 32);
    dn1 += __shfl_xor(dn1, 16); dn1 += __shfl_xor(dn1, 32);
    if (quad == 0) {
        denomp[jq][whead][nn] = dn0;
        denomp[jq][whead][16 + nn] = dn1;
    }
    if (jq > 0) {
#pragma unroll
        for (int s = 0; s < 2; s++)
#pragma unroll
            for (int nt = 0; nt < 4; nt++)
                *(f32x4*)&cmb[whead][jq - 1][lane][s * 16 + nt * 4] = acc[s][nt];
    }
    __syncthreads();
    if (jq == 0) {
#pragma unroll
        for (int s = 0; s < 2; s++) {
#pragma unroll
            for (int nt = 0; nt < 4; nt++) {
                f32x4 o = acc[s][nt]
                        + *(const f32x4*)&cmb[whead][0][lane][s * 16 + nt * 4]
                        + *(const f32x4*)&cmb[whead][1][lane][s * 16 + nt * 4]
                        + *(const f32x4*)&cmb[whead][2][lane][s * 16 + nt * 4];
#pragma unroll
                for (int rr = 0; rr < 4; rr++) {
                    int il = s * 16 + quad * 4 + rr;
                    float dnm = fmaxf(denomp[0][whead][il] + denomp[1][whead][il]
                                    + denomp[2][whead][il] + denomp[3][whead][il], 1e-30f);
                    float v = o[rr] / dnm;
                    v = v > 0.f ? v : __expf(v) - 1.f;
                    out[(unsigned)(i0 + il) * 512 + hb * 128 + whead * 64 + nt * 16 + nn] = v;
                }
            }
        }
    }
}

extern "C" void kernel_launch(void* const* d_in, const int* in_sizes, int n_in,
                              void* d_out, int out_size, void* d_ws, size_t ws_size,
                              hipStream_t stream) {
    const float* h   = (const float*)d_in[0];   // 4096 x 512 fp32
    const int*   adj = (const int*)d_in[1];     // 4096 x 4096 int32
    const float* W   = (const float*)d_in[2];   // 512 x 512 fp32
    const float* a   = (const float*)d_in[3];   // 128 fp32

    char* ws = (char*)d_ws;
    ushort_t* WhT = (ushort_t*)ws;                           // 4 MB
    ushort_t* WT  = (ushort_t*)(ws + (4u << 20));            // 512 KB (also overread pad)
    float* expA = (float*)(ws + (4u << 20) + (512u << 10));  // 4 x 128 KB
    float* expC = expA + 8 * 4096;
    float* expB = expC + 8 * 4096;
    float* expD = expB + 8 * 4096;
    unsigned char* pkm = (unsigned char*)(ws + (5u << 20));  // 2 MB bitmask

    transpose_w<<<256, 256, 0, stream>>>(W, WT);
    gemm_pack<<<1536, 256, 0, stream>>>(WT, h, a, WhT, expA, expC, expB, expD,
                                        adj, pkm);
    gat_attn<<<512, 512, 0, stream>>>(pkm, WhT, expA, expC, expB, expD,
                                      (float*)d_out);
}

// Round 8
// 199.959 us; speedup vs baseline: 1.7325x; 1.7325x over previous
//
#include <hip/hip_runtime.h>
#include <hip/hip_bf16.h>

// fp32 inputs (confirmed r2). Internal pipeline bf16 MFMA.
// Gen identity: w = exp2(max(e,0.2e)) = max(A_i*B_j, C_i*D_j).
// r20 = barrier-free direct-load attn, allocator-fixed.
//   r18/r19 both spilled (183/674 MB scratch) with VGPR_Count pinned at 64
//   under launch_bounds(512,4) despite a ~110-reg live set fitting the 128
//   budget -> the 2nd arg over-constrained the allocator into 64+spill.
//   Fix: launch_bounds(512,2) (floor, not target; 256-reg ceiling). If alloc
//   lands <=128 we still get 4 waves/EU at runtime.
//   - pv SINGLE-deep: refill kb+1 after MFMA cluster; consumed after next
//     phase's ~350cy gen >> 200cy L2 latency.
//   - pBD 2-deep parity (consumed at phase START -> needs 2-phase slack).
//   - denominator via MFMA accd (AGPR-resident, fewer VALU than r19's dn).
//   Wave independence verified: each wave's V slice (64 rows x 32 j-cols) is
//   disjoint and exactly its own loads -> no barriers needed, waves free-run.
//   All loads unconditional; tail overreads land in mapped ws (WT/expD/pkm).
// Mask layout: byte pk[i*512 + g*32 + kb] bits r for j = kb*128 + (g>>2)*32 + (g&3)*8 + r.

typedef unsigned short ushort_t;
typedef __attribute__((ext_vector_type(8))) short bf16x8;
typedef __attribute__((ext_vector_type(4))) float f32x4;

#define LOG2E 1.4426950408889634f

__device__ __forceinline__ ushort_t f2bf(float x) {
    unsigned u = __builtin_bit_cast(unsigned, x);
    u += 0x7FFFu + ((u >> 16) & 1u);   // RNE
    return (ushort_t)(u >> 16);
}

// ---------------- kernel 1: WT[c][k] = W[k][c], 512x512, fp32 -> bf16 ----------------
__global__ __launch_bounds__(256) void transpose_w(const float* __restrict__ W,
                                                   ushort_t* __restrict__ WT) {
    __shared__ ushort_t t[32][33];
    int bx = blockIdx.x & 15, by = blockIdx.x >> 4;
    int tx = threadIdx.x & 31, ty = threadIdx.x >> 5;
#pragma unroll
    for (int i = 0; i < 32; i += 8)
        t[ty + i][tx] = f2bf(W[(by * 32 + ty + i) * 512 + bx * 32 + tx]);
    __syncthreads();
#pragma unroll
    for (int i = 0; i < 32; i += 8)
        WT[(bx * 32 + ty + i) * 512 + by * 32 + tx] = t[tx][ty + i];
}

// -------- kernel 2 (fused): blocks 0-511 = gemm (r8 proven body); 512-1535 = pack ----
__global__ __launch_bounds__(256, 4) void gemm_pack(const ushort_t* __restrict__ WT,
                                                    const float* __restrict__ h,
                                                    const float* __restrict__ a,
                                                    ushort_t* __restrict__ WhT,
                                                    float* __restrict__ expA,
                                                    float* __restrict__ expC,
                                                    float* __restrict__ expB,
                                                    float* __restrict__ expD,
                                                    const int* __restrict__ adj,
                                                    unsigned char* __restrict__ pk) {
    __shared__ __align__(16) ushort_t Al[2][64][72];
    __shared__ __align__(16) ushort_t Bl[2][64][72];
    __shared__ float asrc[64], adst[64];
    __shared__ float sred[2][4][64];
    int tid = threadIdx.x;
    if (blockIdx.x >= 512) {
        // ---------------- pack branch ----------------
        int pbid = blockIdx.x - 512;
        int wv = tid >> 6, lane = tid & 63;
        int row = pbid * 4 + wv;
        const int* ap = adj + (unsigned)row * 4096 + lane;
        unsigned char* pp = pk + (unsigned)row * 512;
        int g = lane;                                 // lanes 0..15 write
        int sv = ((g >> 2) & 1) * 4 + (g & 3);
        int cpar = g >> 3;
#pragma unroll 2
        for (int t = 0; t < 8; t++) {
            unsigned long long m[8];
#pragma unroll
            for (int c8 = 0; c8 < 8; c8++)
                m[c8] = __ballot(ap[(t * 8 + c8) * 64] > 0);
            if (lane < 16) {
                unsigned w = 0;
#pragma unroll
                for (int kq = 0; kq < 4; kq++) {
                    unsigned b = (unsigned)(m[2 * kq + cpar] >> (8 * sv)) & 0xFFu;
                    w |= b << (8 * kq);
                }
                *(unsigned*)(pp + g * 32 + t * 4) = w;
            }
        }
        return;
    }
    // ---------------- gemm branch (r8/r12 proven) ----------------
    int wave = tid >> 6, lane = tid & 63, quad = lane >> 4, nn = lane & 15;
    int mb = blockIdx.x & 7, nb = blockIdx.x >> 3;
    if (tid < 64) {
        asrc[tid] = a[tid] * LOG2E;
        adst[tid] = a[64 + tid] * LOG2E;
    }
    int r = tid >> 2, s0 = tid & 3;
    const ushort_t* Ag = WT + (unsigned)((mb * 64 + r) * 512 + s0 * 8);
    const float* Bg = h + (unsigned)((nb * 64 + r) * 512 + s0 * 8);
    bf16x8 pA0 = *(const bf16x8*)(Ag);
    bf16x8 pA1 = *(const bf16x8*)(Ag + 32);
    float4 pb0 = *(const float4*)(Bg);
    float4 pb1 = *(const float4*)(Bg + 4);
    float4 pb2 = *(const float4*)(Bg + 32);
    float4 pb3 = *(const float4*)(Bg + 36);
    f32x4 acc[4] = {};
#pragma unroll 2
    for (int t = 0; t < 8; t++) {
        int cb = t & 1;
        *(bf16x8*)&Al[cb][r][s0 * 8] = pA0;
        *(bf16x8*)&Al[cb][r][s0 * 8 + 32] = pA1;
        bf16x8 bv;
        bv[0] = (short)f2bf(pb0.x); bv[1] = (short)f2bf(pb0.y);
        bv[2] = (short)f2bf(pb0.z); bv[3] = (short)f2bf(pb0.w);
        bv[4] = (short)f2bf(pb1.x); bv[5] = (short)f2bf(pb1.y);
        bv[6] = (short)f2bf(pb1.z); bv[7] = (short)f2bf(pb1.w);
        *(bf16x8*)&Bl[cb][r][s0 * 8] = bv;
        bv[0] = (short)f2bf(pb2.x); bv[1] = (short)f2bf(pb2.y);
        bv[2] = (short)f2bf(pb2.z); bv[3] = (short)f2bf(pb2.w);
        bv[4] = (short)f2bf(pb3.x); bv[5] = (short)f2bf(pb3.y);
        bv[6] = (short)f2bf(pb3.z); bv[7] = (short)f2bf(pb3.w);
        *(bf16x8*)&Bl[cb][r][s0 * 8 + 32] = bv;
        if (t < 7) {
            int ko = (t + 1) * 64;
            pA0 = *(const bf16x8*)(Ag + ko);
            pA1 = *(const bf16x8*)(Ag + ko + 32);
            pb0 = *(const float4*)(Bg + ko);
            pb1 = *(const float4*)(Bg + ko + 4);
            pb2 = *(const float4*)(Bg + ko + 32);
            pb3 = *(const float4*)(Bg + ko + 36);
        }
        if (t > 0) {
            int pb = cb ^ 1;
            bf16x8 af0 = *(const bf16x8*)&Al[pb][wave * 16 + nn][quad * 8];
            bf16x8 af1 = *(const bf16x8*)&Al[pb][wave * 16 + nn][32 + quad * 8];
#pragma unroll
            for (int nt = 0; nt < 4; nt++) {
                bf16x8 b0 = *(const bf16x8*)&Bl[pb][nt * 16 + nn][quad * 8];
                bf16x8 b1 = *(const bf16x8*)&Bl[pb][nt * 16 + nn][32 + quad * 8];
                acc[nt] = __builtin_amdgcn_mfma_f32_16x16x32_bf16(af0, b0, acc[nt], 0, 0, 0);
                acc[nt] = __builtin_amdgcn_mfma_f32_16x16x32_bf16(af1, b1, acc[nt], 0, 0, 0);
            }
        }
        __syncthreads();
    }
    {
        bf16x8 af0 = *(const bf16x8*)&Al[1][wave * 16 + nn][quad * 8];
        bf16x8 af1 = *(const bf16x8*)&Al[1][wave * 16 + nn][32 + quad * 8];
#pragma unroll
        for (int nt = 0; nt < 4; nt++) {
            bf16x8 b0 = *(const bf16x8*)&Bl[1][nt * 16 + nn][quad * 8];
            bf16x8 b1 = *(const bf16x8*)&Bl[1][nt * 16 + nn][32 + quad * 8];
            acc[nt] = __builtin_amdgcn_mfma_f32_16x16x32_bf16(af0, b0, acc[nt], 0, 0, 0);
            acc[nt] = __builtin_amdgcn_mfma_f32_16x16x32_bf16(af1, b1, acc[nt], 0, 0, 0);
        }
    }
    int row0 = mb * 64 + wave * 16 + quad * 4;
    int col0 = nb * 64 + nn;
    int f0i = wave * 16 + quad * 4;
#pragma unroll
    for (int nt = 0; nt < 4; nt++) {
        float s = 0.f, d = 0.f;
#pragma unroll
        for (int rr = 0; rr < 4; rr++) {
            float v = acc[nt][rr];
            WhT[(unsigned)((row0 + rr) * 4096 + col0 + nt * 16)] = f2bf(v);
            s += v * asrc[f0i + rr];
            d += v * adst[f0i + rr];
        }
        s += __shfl_xor(s, 16); s += __shfl_xor(s, 32);
        d += __shfl_xor(d, 16); d += __shfl_xor(d, 32);
        if (quad == 0) { sred[0][wave][nt * 16 + nn] = s; sred[1][wave][nt * 16 + nn] = d; }
    }
    __syncthreads();
    if (tid < 64) {
        float s = sred[0][0][tid] + sred[0][1][tid] + sred[0][2][tid] + sred[0][3][tid];
        unsigned idx = mb * 4096 + nb * 64 + tid;
        expA[idx] = __builtin_amdgcn_exp2f(s);
        expC[idx] = __builtin_amdgcn_exp2f(0.2f * s);
    } else if (tid < 128) {
        int c = tid - 64;
        float d = sred[1][0][c] + sred[1][1][c] + sred[1][2][c] + sred[1][3][c];
        unsigned idx = mb * 4096 + nb * 64 + c;
        expB[idx] = __builtin_amdgcn_exp2f(d);
        expD[idx] = __builtin_amdgcn_exp2f(0.2f * d);
    }
}

// -------- kernel 3: fused attention, barrier-free, direct V loads, (512,2) ----------
// 512 blocks x 512 thr. wave=(whead, jq); thread gen = A-frags for rows nn and 16+nn
// over j = kb*128 + jq*32 + quad*8 + 0..7. 32 phases, NO in-loop barriers.
// Phase kb: gen from pBD parity slot (kb) -> refill that slot (kb+2) -> MFMA with
// pv (kb) incl. accd denominator -> refill pv (kb+1). All loads unconditional.

// gen one strip: produces AF (bf16x8 A-frag) from pBD values + mask.
#define GEN_STRIP(AF, Ai, Ci, MC, UU, PBD)                                            \
    {                                                                                 \
        unsigned w0, w1, w2, w3, w4, w5, w6, w7;                                      \
        float w;                                                                      \
        w = fmaxf((Ai) * PBD[0].x, (Ci) * PBD[2].x);                                  \
        w0 = __builtin_bit_cast(unsigned, w) & 0xFFFF0000u;                           \
        w0 &= (unsigned)__builtin_amdgcn_sbfe(MC, (UU) * 8 + 0, 1);                   \
        w = fmaxf((Ai) * PBD[0].y, (Ci) * PBD[2].y);                                  \
        w1 = __builtin_bit_cast(unsigned, w) & 0xFFFF0000u;                           \
        w1 &= (unsigned)__builtin_amdgcn_sbfe(MC, (UU) * 8 + 1, 1);                   \
        w = fmaxf((Ai) * PBD[0].z, (Ci) * PBD[2].z);                                  \
        w2 = __builtin_bit_cast(unsigned, w) & 0xFFFF0000u;                           \
        w2 &= (unsigned)__builtin_amdgcn_sbfe(MC, (UU) * 8 + 2, 1);                   \
        w = fmaxf((Ai) * PBD[0].w, (Ci) * PBD[2].w);                                  \
        w3 = __builtin_bit_cast(unsigned, w) & 0xFFFF0000u;                           \
        w3 &= (unsigned)__builtin_amdgcn_sbfe(MC, (UU) * 8 + 3, 1);                   \
        w = fmaxf((Ai) * PBD[1].x, (Ci) * PBD[3].x);                                  \
        w4 = __builtin_bit_cast(unsigned, w) & 0xFFFF0000u;                           \
        w4 &= (unsigned)__builtin_amdgcn_sbfe(MC, (UU) * 8 + 4, 1);                   \
        w = fmaxf((Ai) * PBD[1].y, (Ci) * PBD[3].y);                                  \
        w5 = __builtin_bit_cast(unsigned, w) & 0xFFFF0000u;                           \
        w5 &= (unsigned)__builtin_amdgcn_sbfe(MC, (UU) * 8 + 5, 1);                   \
        w = fmaxf((Ai) * PBD[1].z, (Ci) * PBD[3].z);                                  \
        w6 = __builtin_bit_cast(unsigned, w) & 0xFFFF0000u;                           \
        w6 &= (unsigned)__builtin_amdgcn_sbfe(MC, (UU) * 8 + 6, 1);                   \
        w = fmaxf((Ai) * PBD[1].w, (Ci) * PBD[3].w);                                  \
        w7 = __builtin_bit_cast(unsigned, w) & 0xFFFF0000u;                           \
        w7 &= (unsigned)__builtin_amdgcn_sbfe(MC, (UU) * 8 + 7, 1);                   \
        uint4 pq;                                                                     \
        pq.x = __builtin_amdgcn_perm(w1, w0, 0x07060302u);                            \
        pq.y = __builtin_amdgcn_perm(w3, w2, 0x07060302u);                            \
        pq.z = __builtin_amdgcn_perm(w5, w4, 0x07060302u);                            \
        pq.w = __builtin_amdgcn_perm(w7, w6, 0x07060302u);                            \
        AF = __builtin_bit_cast(bf16x8, pq);                                          \
    }

// Phase kb (UU = kb&3). Entry: Vg/Bp/Dp -> tile kb; PBD holds kb; pv holds kb.
// Exit: PBD refilled kb+2, pv refilled kb+1, pointers advanced one tile.
#define ATT_PHASE(UU, PBD)                                                            \
    {                                                                                 \
        bf16x8 af0, af1;                                                              \
        GEN_STRIP(af0, Ai0, Ci0, mcA, UU, PBD)                                        \
        GEN_STRIP(af1, Ai1, Ci1, mcB, UU, PBD)                                        \
        if (UU == 3) { mcA = mnA; mcB = mnB; }                                        \
        /* refill this pBD parity slot with tile kb+2 (2-phase slack) */              \
        PBD[0] = *(const float4*)(Bp + 256);                                          \
        PBD[1] = *(const float4*)(Bp + 260);                                          \
        PBD[2] = *(const float4*)(Dp + 256);                                          \
        PBD[3] = *(const float4*)(Dp + 260);                                          \
        if (UU == 0) {                                                                \
            mnA = *(const unsigned*)(mpA + 4);                                        \
            mnB = *(const unsigned*)(mpB + 4);                                        \
        }                                                                             \
        __builtin_amdgcn_s_setprio(1);                                                \
        acc[0][0] = __builtin_amdgcn_mfma_f32_16x16x32_bf16(af0, pv[0], acc[0][0], 0, 0, 0); \
        acc[1][0] = __builtin_amdgcn_mfma_f32_16x16x32_bf16(af1, pv[0], acc[1][0], 0, 0, 0); \
        acc[0][1] = __builtin_amdgcn_mfma_f32_16x16x32_bf16(af0, pv[1], acc[0][1], 0, 0, 0); \
        acc[1][1] = __builtin_amdgcn_mfma_f32_16x16x32_bf16(af1, pv[1], acc[1][1], 0, 0, 0); \
        acc[0][2] = __builtin_amdgcn_mfma_f32_16x16x32_bf16(af0, pv[2], acc[0][2], 0, 0, 0); \
        acc[1][2] = __builtin_amdgcn_mfma_f32_16x16x32_bf16(af1, pv[2], acc[1][2], 0, 0, 0); \
        acc[0][3] = __builtin_amdgcn_mfma_f32_16x16x32_bf16(af0, pv[3], acc[0][3], 0, 0, 0); \
        acc[1][3] = __builtin_amdgcn_mfma_f32_16x16x32_bf16(af1, pv[3], acc[1][3], 0, 0, 0); \
        accd[0] = __builtin_amdgcn_mfma_f32_16x16x32_bf16(af0, onef, accd[0], 0, 0, 0);      \
        accd[1] = __builtin_amdgcn_mfma_f32_16x16x32_bf16(af1, onef, accd[1], 0, 0, 0);      \
        __builtin_amdgcn_s_setprio(0);                                                \
        /* refill pv with tile kb+1 (consumed after next phase's gen) */              \
        pv[0] = *(const bf16x8*)(Vg + 128);                                           \
        pv[1] = *(const bf16x8*)(Vg + 128 + 65536);                                   \
        pv[2] = *(const bf16x8*)(Vg + 128 + 131072);                                  \
        pv[3] = *(const bf16x8*)(Vg + 128 + 196608);                                  \
        if (UU == 3) { mpA += 4; mpB += 4; }                                          \
        Vg += 128; Bp += 128; Dp += 128;                                              \
    }

__global__ __launch_bounds__(512, 2) void gat_attn(const unsigned char* __restrict__ pk,
                                                   const ushort_t* __restrict__ WhT,
                                                   const float* __restrict__ expA,
                                                   const float* __restrict__ expC,
                                                   const float* __restrict__ expB,
                                                   const float* __restrict__ expD,
                                                   float* __restrict__ out) {
    __shared__ __align__(16) float cmb[2][3][64][32];   // 49152 B, epilogue combine
    __shared__ float denomp[4][2][32];                  // 1024 B
    int tid = threadIdx.x;
    int wave = tid >> 6, lane = tid & 63, quad = lane >> 4, nn = lane & 15;
    int hb = blockIdx.x >> 7, ib = blockIdx.x & 127;
    int i0 = ib * 32;
    int whead = wave & 1, jq = wave >> 1;              // jq 0..3
    int g = jq * 4 + quad;
    int head = hb * 2 + whead;
    float Ai0 = expA[head * 4096 + i0 + nn];
    float Ci0 = expC[head * 4096 + i0 + nn];
    float Ai1 = expA[head * 4096 + i0 + 16 + nn];
    float Ci1 = expC[head * 4096 + i0 + 16 + nn];
    const unsigned char* mpA = pk + (unsigned)(i0 + nn) * 512 + g * 32;
    const unsigned char* mpB = mpA + 16 * 512;
    const float* Bp = expB + (unsigned)head * 4096 + jq * 32 + quad * 8;
    const float* Dp = expD + (unsigned)head * 4096 + jq * 32 + quad * 8;
    // V fragment base: row (hb*128 + whead*64 + nn), col jq*32 + quad*8; nt adds
    // nt*16 rows = nt*65536 ushorts; per phase the base advances 128 cols.
    const ushort_t* Vg = WhT + (unsigned)(hb * 128 + whead * 64 + nn) * 4096
                             + jq * 32 + quad * 8;
    bf16x8 onef;
#pragma unroll
    for (int i = 0; i < 8; i++) onef[i] = (short)0x3F80;   // bf16 1.0
    f32x4 acc[2][4] = {};
    f32x4 accd[2] = {};
    bf16x8 pv[4];
    float4 pBDa[4], pBDb[4];
    // prologue: pv = tile 0, pBDa = tile 0, pBDb = tile 1
    pv[0] = *(const bf16x8*)(Vg);
    pv[1] = *(const bf16x8*)(Vg + 65536);
    pv[2] = *(const bf16x8*)(Vg + 131072);
    pv[3] = *(const bf16x8*)(Vg + 196608);
    pBDa[0] = *(const float4*)(Bp);
    pBDa[1] = *(const float4*)(Bp + 4);
    pBDa[2] = *(const float4*)(Dp);
    pBDa[3] = *(const float4*)(Dp + 4);
    pBDb[0] = *(const float4*)(Bp + 128);
    pBDb[1] = *(const float4*)(Bp + 132);
    pBDb[2] = *(const float4*)(Dp + 128);
    pBDb[3] = *(const float4*)(Dp + 132);
    unsigned mcA = *(const unsigned*)(mpA);
    unsigned mcB = *(const unsigned*)(mpB);
    unsigned mnA = 0, mnB = 0;
    for (int t = 0; t < 8; t++) {
        ATT_PHASE(0, pBDa)
        ATT_PHASE(1, pBDb)
        ATT_PHASE(2, pBDa)
        ATT_PHASE(3, pBDb)
    }
    // denominator partials: row = s*16 + quad*4 + rr
    if (nn == 0) {
#pragma unroll
        for (int s = 0; s < 2; s++)
#pragma unroll
            for (int rr = 0; rr < 4; rr++)
                denomp[jq][whead][s * 16 + quad * 4 + rr] = accd[s][rr];
    }
    if (jq > 0) {
#pragma unroll
        for (int s = 0; s < 2; s++)
#pragma unroll
            for (int nt = 0; nt < 4; nt++)
                *(f32x4*)&cmb[whead][jq - 1][lane][s * 16 + nt * 4] = acc[s][nt];
    }
    __syncthreads();
    if (jq == 0) {
#pragma unroll
        for (int s = 0; s < 2; s++) {
#pragma unroll
            for (int nt = 0; nt < 4; nt++) {
                f32x4 o = acc[s][nt]
                        + *(const f32x4*)&cmb[whead][0][lane][s * 16 + nt * 4]
                        + *(const f32x4*)&cmb[whead][1][lane][s * 16 + nt * 4]
                        + *(const f32x4*)&cmb[whead][2][lane][s * 16 + nt * 4];
#pragma unroll
                for (int rr = 0; rr < 4; rr++) {
                    int il = s * 16 + quad * 4 + rr;
                    float dnm = fmaxf(denomp[0][whead][il] + denomp[1][whead][il]
                                    + denomp[2][whead][il] + denomp[3][whead][il], 1e-30f);
                    float v = o[rr] / dnm;
                    v = v > 0.f ? v : __expf(v) - 1.f;
                    out[(unsigned)(i0 + il) * 512 + hb * 128 + whead * 64 + nt * 16 + nn] = v;
                }
            }
        }
    }
}

extern "C" void kernel_launch(void* const* d_in, const int* in_sizes, int n_in,
                              void* d_out, int out_size, void* d_ws, size_t ws_size,
                              hipStream_t stream) {
    const float* h   = (const float*)d_in[0];   // 4096 x 512 fp32
    const int*   adj = (const int*)d_in[1];     // 4096 x 4096 int32
    const float* W   = (const float*)d_in[2];   // 512 x 512 fp32
    const float* a   = (const float*)d_in[3];   // 128 fp32

    char* ws = (char*)d_ws;
    ushort_t* WhT = (ushort_t*)ws;                           // 4 MB
    ushort_t* WT  = (ushort_t*)(ws + (4u << 20));            // 512 KB (also overread pad)
    float* expA = (float*)(ws + (4u << 20) + (512u << 10));  // 4 x 128 KB
    float* expC = expA + 8 * 4096;
    float* expB = expC + 8 * 4096;
    float* expD = expB + 8 * 4096;
    unsigned char* pkm = (unsigned char*)(ws + (5u << 20));  // 2 MB bitmask

    transpose_w<<<256, 256, 0, stream>>>(W, WT);
    gemm_pack<<<1536, 256, 0, stream>>>(WT, h, a, WhT, expA, expC, expB, expD,
                                        adj, pkm);
    gat_attn<<<512, 512, 0, stream>>>(pkm, WhT, expA, expC, expB, expD,
                                      (float*)d_out);
}

// Round 9
// 175.784 us; speedup vs baseline: 1.9708x; 1.1375x over previous
//
#include <hip/hip_runtime.h>
#include <hip/hip_bf16.h>

// fp32 inputs (confirmed r2). Internal pipeline bf16 MFMA.
// Gen identity: w = exp2(max(e,0.2e)) = max(A_i*B_j, C_i*D_j).
// r21 = r17 structure (j-tile 128, double-buffer Vb, 1 barrier/iter, fused pack)
//   with V staging via global_load_lds width=16 (DMA, no VGPR round-trip):
//   - LDS dest linear (HW: uniform base + lane*16); bank swizzle moved to the
//     GLOBAL source address (rule #21): r17's key(r)=((r&3)<<2)|((r>>2)&3)
//     collapses per-lane to key=((l>>4)<<2)|q -> source granule (l&15)^key.
//   - read side byte-identical to r17's rcol (proven correct, <=2-way banks).
//   - removes 4 ds_write_b128/thread/phase + pv regs (16) + the phase-start
//     vmcnt convoy; the per-phase syncthreads drain makes the DMA visible.
//   r18-r20 direct-load family: closed (clean r20 = 93us, latency-bound at
//   4 waves/SIMD; falsifier fired). r13/r17 staged structure is the platform.
// Mask layout: byte pk[i*512 + g*32 + kb] bits r for j = kb*128 + (g>>2)*32 + (g&3)*8 + r.

typedef unsigned short ushort_t;
typedef __attribute__((ext_vector_type(8))) short bf16x8;
typedef __attribute__((ext_vector_type(4))) float f32x4;

#define LOG2E 1.4426950408889634f

__device__ __forceinline__ ushort_t f2bf(float x) {
    unsigned u = __builtin_bit_cast(unsigned, x);
    u += 0x7FFFu + ((u >> 16) & 1u);   // RNE
    return (ushort_t)(u >> 16);
}

__device__ __forceinline__ void gload16(const void* g, void* l) {
    __builtin_amdgcn_global_load_lds(
        (const __attribute__((address_space(1))) unsigned int*)g,
        (__attribute__((address_space(3))) unsigned int*)l, 16, 0, 0);
}

// ---------------- kernel 1: WT[c][k] = W[k][c], 512x512, fp32 -> bf16 ----------------
__global__ __launch_bounds__(256) void transpose_w(const float* __restrict__ W,
                                                   ushort_t* __restrict__ WT) {
    __shared__ ushort_t t[32][33];
    int bx = blockIdx.x & 15, by = blockIdx.x >> 4;
    int tx = threadIdx.x & 31, ty = threadIdx.x >> 5;
#pragma unroll
    for (int i = 0; i < 32; i += 8)
        t[ty + i][tx] = f2bf(W[(by * 32 + ty + i) * 512 + bx * 32 + tx]);
    __syncthreads();
#pragma unroll
    for (int i = 0; i < 32; i += 8)
        WT[(bx * 32 + ty + i) * 512 + by * 32 + tx] = t[tx][ty + i];
}

// -------- kernel 2 (fused): blocks 0-511 = gemm (r8 proven body); 512-1535 = pack ----
__global__ __launch_bounds__(256, 4) void gemm_pack(const ushort_t* __restrict__ WT,
                                                    const float* __restrict__ h,
                                                    const float* __restrict__ a,
                                                    ushort_t* __restrict__ WhT,
                                                    float* __restrict__ expA,
                                                    float* __restrict__ expC,
                                                    float* __restrict__ expB,
                                                    float* __restrict__ expD,
                                                    const int* __restrict__ adj,
                                                    unsigned char* __restrict__ pk) {
    __shared__ __align__(16) ushort_t Al[2][64][72];
    __shared__ __align__(16) ushort_t Bl[2][64][72];
    __shared__ float asrc[64], adst[64];
    __shared__ float sred[2][4][64];
    int tid = threadIdx.x;
    if (blockIdx.x >= 512) {
        // ---------------- pack branch ----------------
        int pbid = blockIdx.x - 512;
        int wv = tid >> 6, lane = tid & 63;
        int row = pbid * 4 + wv;
        const int* ap = adj + (unsigned)row * 4096 + lane;
        unsigned char* pp = pk + (unsigned)row * 512;
        int g = lane;                                 // lanes 0..15 write
        int sv = ((g >> 2) & 1) * 4 + (g & 3);
        int cpar = g >> 3;
#pragma unroll 2
        for (int t = 0; t < 8; t++) {
            unsigned long long m[8];
#pragma unroll
            for (int c8 = 0; c8 < 8; c8++)
                m[c8] = __ballot(ap[(t * 8 + c8) * 64] > 0);
            if (lane < 16) {
                unsigned w = 0;
#pragma unroll
                for (int kq = 0; kq < 4; kq++) {
                    unsigned b = (unsigned)(m[2 * kq + cpar] >> (8 * sv)) & 0xFFu;
                    w |= b << (8 * kq);
                }
                *(unsigned*)(pp + g * 32 + t * 4) = w;
            }
        }
        return;
    }
    // ---------------- gemm branch (r8/r12 proven) ----------------
    int wave = tid >> 6, lane = tid & 63, quad = lane >> 4, nn = lane & 15;
    int mb = blockIdx.x & 7, nb = blockIdx.x >> 3;
    if (tid < 64) {
        asrc[tid] = a[tid] * LOG2E;
        adst[tid] = a[64 + tid] * LOG2E;
    }
    int r = tid >> 2, s0 = tid & 3;
    const ushort_t* Ag = WT + (unsigned)((mb * 64 + r) * 512 + s0 * 8);
    const float* Bg = h + (unsigned)((nb * 64 + r) * 512 + s0 * 8);
    bf16x8 pA0 = *(const bf16x8*)(Ag);
    bf16x8 pA1 = *(const bf16x8*)(Ag + 32);
    float4 pb0 = *(const float4*)(Bg);
    float4 pb1 = *(const float4*)(Bg + 4);
    float4 pb2 = *(const float4*)(Bg + 32);
    float4 pb3 = *(const float4*)(Bg + 36);
    f32x4 acc[4] = {};
#pragma unroll 2
    for (int t = 0; t < 8; t++) {
        int cb = t & 1;
        *(bf16x8*)&Al[cb][r][s0 * 8] = pA0;
        *(bf16x8*)&Al[cb][r][s0 * 8 + 32] = pA1;
        bf16x8 bv;
        bv[0] = (short)f2bf(pb0.x); bv[1] = (short)f2bf(pb0.y);
        bv[2] = (short)f2bf(pb0.z); bv[3] = (short)f2bf(pb0.w);
        bv[4] = (short)f2bf(pb1.x); bv[5] = (short)f2bf(pb1.y);
        bv[6] = (short)f2bf(pb1.z); bv[7] = (short)f2bf(pb1.w);
        *(bf16x8*)&Bl[cb][r][s0 * 8] = bv;
        bv[0] = (short)f2bf(pb2.x); bv[1] = (short)f2bf(pb2.y);
        bv[2] = (short)f2bf(pb2.z); bv[3] = (short)f2bf(pb2.w);
        bv[4] = (short)f2bf(pb3.x); bv[5] = (short)f2bf(pb3.y);
        bv[6] = (short)f2bf(pb3.z); bv[7] = (short)f2bf(pb3.w);
        *(bf16x8*)&Bl[cb][r][s0 * 8 + 32] = bv;
        if (t < 7) {
            int ko = (t + 1) * 64;
            pA0 = *(const bf16x8*)(Ag + ko);
            pA1 = *(const bf16x8*)(Ag + ko + 32);
            pb0 = *(const float4*)(Bg + ko);
            pb1 = *(const float4*)(Bg + ko + 4);
            pb2 = *(const float4*)(Bg + ko + 32);
            pb3 = *(const float4*)(Bg + ko + 36);
        }
        if (t > 0) {
            int pb = cb ^ 1;
            bf16x8 af0 = *(const bf16x8*)&Al[pb][wave * 16 + nn][quad * 8];
            bf16x8 af1 = *(const bf16x8*)&Al[pb][wave * 16 + nn][32 + quad * 8];
#pragma unroll
            for (int nt = 0; nt < 4; nt++) {
                bf16x8 b0 = *(const bf16x8*)&Bl[pb][nt * 16 + nn][quad * 8];
                bf16x8 b1 = *(const bf16x8*)&Bl[pb][nt * 16 + nn][32 + quad * 8];
                acc[nt] = __builtin_amdgcn_mfma_f32_16x16x32_bf16(af0, b0, acc[nt], 0, 0, 0);
                acc[nt] = __builtin_amdgcn_mfma_f32_16x16x32_bf16(af1, b1, acc[nt], 0, 0, 0);
            }
        }
        __syncthreads();
    }
    {
        bf16x8 af0 = *(const bf16x8*)&Al[1][wave * 16 + nn][quad * 8];
        bf16x8 af1 = *(const bf16x8*)&Al[1][wave * 16 + nn][32 + quad * 8];
#pragma unroll
        for (int nt = 0; nt < 4; nt++) {
            bf16x8 b0 = *(const bf16x8*)&Bl[1][nt * 16 + nn][quad * 8];
            bf16x8 b1 = *(const bf16x8*)&Bl[1][nt * 16 + nn][32 + quad * 8];
            acc[nt] = __builtin_amdgcn_mfma_f32_16x16x32_bf16(af0, b0, acc[nt], 0, 0, 0);
            acc[nt] = __builtin_amdgcn_mfma_f32_16x16x32_bf16(af1, b1, acc[nt], 0, 0, 0);
        }
    }
    int row0 = mb * 64 + wave * 16 + quad * 4;
    int col0 = nb * 64 + nn;
    int f0i = wave * 16 + quad * 4;
#pragma unroll
    for (int nt = 0; nt < 4; nt++) {
        float s = 0.f, d = 0.f;
#pragma unroll
        for (int rr = 0; rr < 4; rr++) {
            float v = acc[nt][rr];
            WhT[(unsigned)((row0 + rr) * 4096 + col0 + nt * 16)] = f2bf(v);
            s += v * asrc[f0i + rr];
            d += v * adst[f0i + rr];
        }
        s += __shfl_xor(s, 16); s += __shfl_xor(s, 32);
        d += __shfl_xor(d, 16); d += __shfl_xor(d, 32);
        if (quad == 0) { sred[0][wave][nt * 16 + nn] = s; sred[1][wave][nt * 16 + nn] = d; }
    }
    __syncthreads();
    if (tid < 64) {
        float s = sred[0][0][tid] + sred[0][1][tid] + sred[0][2][tid] + sred[0][3][tid];
        unsigned idx = mb * 4096 + nb * 64 + tid;
        expA[idx] = __builtin_amdgcn_exp2f(s);
        expC[idx] = __builtin_amdgcn_exp2f(0.2f * s);
    } else if (tid < 128) {
        int c = tid - 64;
        float d = sred[1][0][c] + sred[1][1][c] + sred[1][2][c] + sred[1][3][c];
        unsigned idx = mb * 4096 + nb * 64 + c;
        expB[idx] = __builtin_amdgcn_exp2f(d);
        expD[idx] = __builtin_amdgcn_exp2f(0.2f * d);
    }
}

// -------- kernel 3: fused attention, j-tile 128, global_load_lds staging ------------
// 512 blocks x 512 thr (512,4). wave=(whead, jq); thread gen = A-frags for rows
// nn and 16+nn over j = kb*128 + jq*32 + quad*8 + 0..7. 32 iters, 1 barrier each.
// Vb[2][128][128]: element (row, col) at in-row byte (col*2)^(key(row)<<4),
// key(r) = ((r&3)<<2)|((r>>2)&3). Staged by DMA: wave w, seg q covers rows
// w*16+q*4..+3 linearly; lane l fetches global granule (l&15)^((l>>4)<<2)^q.
// Read rcol identical to r17 (proven). The per-phase barrier drain (vmcnt 0)
// makes tile kb's DMA visible before its MFMAs.
__global__ __launch_bounds__(512, 4) void gat_attn(const unsigned char* __restrict__ pk,
                                                   const ushort_t* __restrict__ WhT,
                                                   const float* __restrict__ expA,
                                                   const float* __restrict__ expC,
                                                   const float* __restrict__ expB,
                                                   const float* __restrict__ expD,
                                                   float* __restrict__ out) {
    __shared__ __align__(16) ushort_t Vb[2][128][128];   // 65536 B (cmb overlays)
    __shared__ float denomp[4][2][32];
    int tid = threadIdx.x;
    int wave = tid >> 6, lane = tid & 63, quad = lane >> 4, nn = lane & 15;
    int hb = blockIdx.x >> 7, ib = blockIdx.x & 127;   // adj row-band on one XCD
    int i0 = ib * 32;
    int whead = wave & 1, jq = wave >> 1;              // jq 0..3
    int g = jq * 4 + quad;
    int head = hb * 2 + whead;
    float Ai0 = expA[head * 4096 + i0 + nn];
    float Ci0 = expC[head * 4096 + i0 + nn];
    float Ai1 = expA[head * 4096 + i0 + 16 + nn];
    float Ci1 = expC[head * 4096 + i0 + 16 + nn];
    const unsigned char* mpA = pk + (unsigned)(i0 + nn) * 512 + g * 32;
    const unsigned char* mpB = mpA + 16 * 512;
    const float* Bp = expB + (unsigned)head * 4096 + jq * 32 + quad * 8;
    const float* Dp = expD + (unsigned)head * 4096 + jq * 32 + quad * 8;
    // ---- staging source pointers (4 segs/thread), pre-swizzled global granule ----
    int hh = lane >> 4, lg = lane & 15;
    const ushort_t* stg0 = WhT + (unsigned)(hb * 128 + wave * 16 + 0 + hh) * 4096
                               + ((lg ^ (hh << 2) ^ 0) * 8);
    const ushort_t* stg1 = WhT + (unsigned)(hb * 128 + wave * 16 + 4 + hh) * 4096
                               + ((lg ^ (hh << 2) ^ 1) * 8);
    const ushort_t* stg2 = WhT + (unsigned)(hb * 128 + wave * 16 + 8 + hh) * 4096
                               + ((lg ^ (hh << 2) ^ 2) * 8);
    const ushort_t* stg3 = WhT + (unsigned)(hb * 128 + wave * 16 + 12 + hh) * 4096
                               + ((lg ^ (hh << 2) ^ 3) * 8);
    char* lwb = (char*)&Vb[0][0][0] + wave * 4096;     // wave's LDS write base (buf 0)
    // MFMA B-frag read: logical col jq*32 + quad*8 -> byte (jq*64+quad*16)^(key(nn)<<4)
    int rcol = (jq * 64 + quad * 16) ^ ((((nn & 3) << 2) | ((nn >> 2) & 3)) << 4);
    const char* vrb = (const char*)&Vb[0][0][0] + (whead * 64 + nn) * 256 + rcol;
    bf16x8 onef;
#pragma unroll
    for (int i = 0; i < 8; i++) onef[i] = (short)0x3F80;   // bf16 1.0
    f32x4 acc[2][4] = {};
    f32x4 accd[2] = {};
    float4 pBD[4];
    // prologue: DMA tile 0 -> buf0; pBD tile 0; masks
    gload16(stg0, lwb);
    gload16(stg1, lwb + 1024);
    gload16(stg2, lwb + 2048);
    gload16(stg3, lwb + 3072);
    pBD[0] = *(const float4*)(Bp);
    pBD[1] = *(const float4*)(Bp + 4);
    pBD[2] = *(const float4*)(Dp);
    pBD[3] = *(const float4*)(Dp + 4);
    unsigned mcA = *(const unsigned*)(mpA);
    unsigned mcB = *(const unsigned*)(mpB);
    unsigned mnA = 0, mnB = 0;
    for (int t = 0; t < 8; t++) {
#pragma unroll
        for (int u = 0; u < 4; u++) {
            int kb = t * 4 + u;
            int cb = u & 1;                      // tile kb lives in buffer kb&1
            // ---- gen both strips (shared B/D) ----
            float4 Bv0 = pBD[0], Bv1 = pBD[1], Dv0 = pBD[2], Dv1 = pBD[3];
            bf16x8 af0, af1;
            {
                unsigned w0, w1, w2, w3, w4, w5, w6, w7;
                float w;
                w = fmaxf(Ai0 * Bv0.x, Ci0 * Dv0.x);
                w0 = __builtin_bit_cast(unsigned, w) & 0xFFFF0000u;
                w0 &= (unsigned)__builtin_amdgcn_sbfe(mcA, u * 8 + 0, 1);
                w = fmaxf(Ai0 * Bv0.y, Ci0 * Dv0.y);
                w1 = __builtin_bit_cast(unsigned, w) & 0xFFFF0000u;
                w1 &= (unsigned)__builtin_amdgcn_sbfe(mcA, u * 8 + 1, 1);
                w = fmaxf(Ai0 * Bv0.z, Ci0 * Dv0.z);
                w2 = __builtin_bit_cast(unsigned, w) & 0xFFFF0000u;
                w2 &= (unsigned)__builtin_amdgcn_sbfe(mcA, u * 8 + 2, 1);
                w = fmaxf(Ai0 * Bv0.w, Ci0 * Dv0.w);
                w3 = __builtin_bit_cast(unsigned, w) & 0xFFFF0000u;
                w3 &= (unsigned)__builtin_amdgcn_sbfe(mcA, u * 8 + 3, 1);
                w = fmaxf(Ai0 * Bv1.x, Ci0 * Dv1.x);
                w4 = __builtin_bit_cast(unsigned, w) & 0xFFFF0000u;
                w4 &= (unsigned)__builtin_amdgcn_sbfe(mcA, u * 8 + 4, 1);
                w = fmaxf(Ai0 * Bv1.y, Ci0 * Dv1.y);
                w5 = __builtin_bit_cast(unsigned, w) & 0xFFFF0000u;
                w5 &= (unsigned)__builtin_amdgcn_sbfe(mcA, u * 8 + 5, 1);
                w = fmaxf(Ai0 * Bv1.z, Ci0 * Dv1.z);
                w6 = __builtin_bit_cast(unsigned, w) & 0xFFFF0000u;
                w6 &= (unsigned)__builtin_amdgcn_sbfe(mcA, u * 8 + 6, 1);
                w = fmaxf(Ai0 * Bv1.w, Ci0 * Dv1.w);
                w7 = __builtin_bit_cast(unsigned, w) & 0xFFFF0000u;
                w7 &= (unsigned)__builtin_amdgcn_sbfe(mcA, u * 8 + 7, 1);
                uint4 pq;
                pq.x = __builtin_amdgcn_perm(w1, w0, 0x07060302u);
                pq.y = __builtin_amdgcn_perm(w3, w2, 0x07060302u);
                pq.z = __builtin_amdgcn_perm(w5, w4, 0x07060302u);
                pq.w = __builtin_amdgcn_perm(w7, w6, 0x07060302u);
                af0 = __builtin_bit_cast(bf16x8, pq);
                w = fmaxf(Ai1 * Bv0.x, Ci1 * Dv0.x);
                w0 = __builtin_bit_cast(unsigned, w) & 0xFFFF0000u;
                w0 &= (unsigned)__builtin_amdgcn_sbfe(mcB, u * 8 + 0, 1);
                w = fmaxf(Ai1 * Bv0.y, Ci1 * Dv0.y);
                w1 = __builtin_bit_cast(unsigned, w) & 0xFFFF0000u;
                w1 &= (unsigned)__builtin_amdgcn_sbfe(mcB, u * 8 + 1, 1);
                w = fmaxf(Ai1 * Bv0.z, Ci1 * Dv0.z);
                w2 = __builtin_bit_cast(unsigned, w) & 0xFFFF0000u;
                w2 &= (unsigned)__builtin_amdgcn_sbfe(mcB, u * 8 + 2, 1);
                w = fmaxf(Ai1 * Bv0.w, Ci1 * Dv0.w);
                w3 = __builtin_bit_cast(unsigned, w) & 0xFFFF0000u;
                w3 &= (unsigned)__builtin_amdgcn_sbfe(mcB, u * 8 + 3, 1);
                w = fmaxf(Ai1 * Bv1.x, Ci1 * Dv1.x);
                w4 = __builtin_bit_cast(unsigned, w) & 0xFFFF0000u;
                w4 &= (unsigned)__builtin_amdgcn_sbfe(mcB, u * 8 + 4, 1);
                w = fmaxf(Ai1 * Bv1.y, Ci1 * Dv1.y);
                w5 = __builtin_bit_cast(unsigned, w) & 0xFFFF0000u;
                w5 &= (unsigned)__builtin_amdgcn_sbfe(mcB, u * 8 + 5, 1);
                w = fmaxf(Ai1 * Bv1.z, Ci1 * Dv1.z);
                w6 = __builtin_bit_cast(unsigned, w) & 0xFFFF0000u;
                w6 &= (unsigned)__builtin_amdgcn_sbfe(mcB, u * 8 + 6, 1);
                w = fmaxf(Ai1 * Bv1.w, Ci1 * Dv1.w);
                w7 = __builtin_bit_cast(unsigned, w) & 0xFFFF0000u;
                w7 &= (unsigned)__builtin_amdgcn_sbfe(mcB, u * 8 + 7, 1);
                pq.x = __builtin_amdgcn_perm(w1, w0, 0x07060302u);
                pq.y = __builtin_amdgcn_perm(w3, w2, 0x07060302u);
                pq.z = __builtin_amdgcn_perm(w5, w4, 0x07060302u);
                pq.w = __builtin_amdgcn_perm(w7, w6, 0x07060302u);
                af1 = __builtin_bit_cast(bf16x8, pq);
            }
            if (u == 3) { mcA = mnA; mcB = mnB; }
            // ---- barrier: drains tile-kb DMA (vmcnt 0) + ends tile-(kb-1) reads ----
            __syncthreads();
            __builtin_amdgcn_sched_barrier(0);     // pin: issues below stay below
            // ---- issue DMA for tile kb+1 into buffer cb^1; pBD prefetch ----
            if (kb < 31) {
                char* lb = (char*)&Vb[0][0][0] + wave * 4096 + ((cb ^ 1) << 15);
                gload16(stg0 + 128, lb);
                gload16(stg1 + 128, lb + 1024);
                gload16(stg2 + 128, lb + 2048);
                gload16(stg3 + 128, lb + 3072);
                stg0 += 128; stg1 += 128; stg2 += 128; stg3 += 128;
                pBD[0] = *(const float4*)(Bp + (kb + 1) * 128);
                pBD[1] = *(const float4*)(Bp + (kb + 1) * 128 + 4);
                pBD[2] = *(const float4*)(Dp + (kb + 1) * 128);
                pBD[3] = *(const float4*)(Dp + (kb + 1) * 128 + 4);
            }
            if (u == 0 && t < 7) {
                mnA = *(const unsigned*)(mpA + (t + 1) * 4);
                mnB = *(const unsigned*)(mpB + (t + 1) * 4);
            }
            // ---- MFMA tile kb from buffer cb: each bv feeds both strips ----
#pragma unroll
            for (int nt = 0; nt < 4; nt++) {
                bf16x8 bv = *(const bf16x8*)(vrb + (cb << 15) + nt * 4096);
                acc[0][nt] = __builtin_amdgcn_mfma_f32_16x16x32_bf16(af0, bv, acc[0][nt], 0, 0, 0);
                acc[1][nt] = __builtin_amdgcn_mfma_f32_16x16x32_bf16(af1, bv, acc[1][nt], 0, 0, 0);
            }
            accd[0] = __builtin_amdgcn_mfma_f32_16x16x32_bf16(af0, onef, accd[0], 0, 0, 0);
            accd[1] = __builtin_amdgcn_mfma_f32_16x16x32_bf16(af1, onef, accd[1], 0, 0, 0);
        }
    }
    __syncthreads();   // all Vb reads of tile 31 done before cmb overlay writes
    // denominator partials: row = s*16 + quad*4 + rr
    if (nn == 0) {
#pragma unroll
        for (int s = 0; s < 2; s++)
#pragma unroll
            for (int rr = 0; rr < 4; rr++)
                denomp[jq][whead][s * 16 + quad * 4 + rr] = accd[s][rr];
    }
    // combine jq partials via cmb overlay on Vb (49152 B <= 65536 B)
    float (*cmb)[3][64][32] = reinterpret_cast<float (*)[3][64][32]>(&Vb[0][0][0]);
    if (jq > 0) {
#pragma unroll
        for (int s = 0; s < 2; s++)
#pragma unroll
            for (int nt = 0; nt < 4; nt++)
                *(f32x4*)&cmb[whead][jq - 1][lane][s * 16 + nt * 4] = acc[s][nt];
    }
    __syncthreads();
    if (jq == 0) {
#pragma unroll
        for (int s = 0; s < 2; s++) {
#pragma unroll
            for (int nt = 0; nt < 4; nt++) {
                f32x4 o = acc[s][nt]
                        + *(const f32x4*)&cmb[whead][0][lane][s * 16 + nt * 4]
                        + *(const f32x4*)&cmb[whead][1][lane][s * 16 + nt * 4]
                        + *(const f32x4*)&cmb[whead][2][lane][s * 16 + nt * 4];
#pragma unroll
                for (int rr = 0; rr < 4; rr++) {
                    int il = s * 16 + quad * 4 + rr;
                    float dnm = fmaxf(denomp[0][whead][il] + denomp[1][whead][il]
                                    + denomp[2][whead][il] + denomp[3][whead][il], 1e-30f);
                    float v = o[rr] / dnm;
                    v = v > 0.f ? v : __expf(v) - 1.f;
                    out[(unsigned)(i0 + il) * 512 + hb * 128 + whead * 64 + nt * 16 + nn] = v;
                }
            }
        }
    }
}

extern "C" void kernel_launch(void* const* d_in, const int* in_sizes, int n_in,
                              void* d_out, int out_size, void* d_ws, size_t ws_size,
                              hipStream_t stream) {
    const float* h   = (const float*)d_in[0];   // 4096 x 512 fp32
    const int*   adj = (const int*)d_in[1];     // 4096 x 4096 int32
    const float* W   = (const float*)d_in[2];   // 512 x 512 fp32
    const float* a   = (const float*)d_in[3];   // 128 fp32

    char* ws = (char*)d_ws;
    ushort_t* WhT = (ushort_t*)ws;                           // 4 MB
    ushort_t* WT  = (ushort_t*)(ws + (4u << 20));            // 512 KB
    float* expA = (float*)(ws + (4u << 20) + (512u << 10));  // 4 x 128 KB
    float* expC = expA + 8 * 4096;
    float* expB = expC + 8 * 4096;
    float* expD = expB + 8 * 4096;
    unsigned char* pkm = (unsigned char*)(ws + (5u << 20));  // 2 MB bitmask

    transpose_w<<<256, 256, 0, stream>>>(W, WT);
    gemm_pack<<<1536, 256, 0, stream>>>(WT, h, a, WhT, expA, expC, expB, expD,
                                        adj, pkm);
    gat_attn<<<512, 512, 0, stream>>>(pkm, WhT, expA, expC, expB, expD,
                                      (float*)d_out);
}

// Round 10
// 167.906 us; speedup vs baseline: 2.0633x; 1.0469x over previous
//
#include <hip/hip_runtime.h>
#include <hip/hip_bf16.h>

// fp32 inputs (confirmed r2). Internal pipeline bf16 MFMA.
// Gen identity: w = exp2(max(e,0.2e)) = max(A_i*B_j, C_i*D_j).
// r22 = attack the OTHER half: residual (total - gat_attn) is a stable
//   ~107-111us across all clean rounds = gemm_pack + transpose_w + gaps,
//   vs a ~15-20us roofline for gemm_pack (GEMM 2.15GF ~7us, adj 64MB ~10us).
//   - h fp32 -> bf16 pre-converted ONCE (fused into transpose_w, blocks >=256):
//     kills the 8x-redundant per-tile f2bf (16/thread/t-iter) on the gemm
//     staging critical path and halves B staging bytes. Bit-identical RNE.
//   - gemm branch stages B exactly like A (two bf16x8 copies).
//   - gat_attn: EXACT r13 revert (59.5us local optimum; r17 swizzle 61.2,
//     r21 DMA 65.0 -> staging micro-structure is dead, lever closed).
// Mask layout: byte pk[i*512 + g*32 + kb] bits r for j = kb*128 + (g>>2)*32 + (g&3)*8 + r.

typedef unsigned short ushort_t;
typedef __attribute__((ext_vector_type(8))) short bf16x8;
typedef __attribute__((ext_vector_type(4))) float f32x4;

#define LOG2E 1.4426950408889634f

__device__ __forceinline__ ushort_t f2bf(float x) {
    unsigned u = __builtin_bit_cast(unsigned, x);
    u += 0x7FFFu + ((u >> 16) & 1u);   // RNE
    return (ushort_t)(u >> 16);
}

// ---- kernel 1 (fused): blocks 0-255 = WT[c][k]=W[k][c]; 256-767 = h -> bf16 --------
__global__ __launch_bounds__(256) void transpose_w(const float* __restrict__ W,
                                                   ushort_t* __restrict__ WT,
                                                   const float* __restrict__ h,
                                                   ushort_t* __restrict__ hB) {
    if (blockIdx.x >= 256) {
        // h convert branch: 512 blocks x 4096 elems (coalesced float4 -> ushort4)
        int b = blockIdx.x - 256;
        const float* src = h + (unsigned)b * 4096;
        ushort_t* dst = hB + (unsigned)b * 4096;
#pragma unroll
        for (int j = 0; j < 4; j++) {
            int e = j * 1024 + threadIdx.x * 4;
            float4 v = *(const float4*)(src + e);
            ushort4 o;
            o.x = f2bf(v.x); o.y = f2bf(v.y); o.z = f2bf(v.z); o.w = f2bf(v.w);
            *(ushort4*)(dst + e) = o;
        }
        return;
    }
    __shared__ ushort_t t[32][33];
    int bx = blockIdx.x & 15, by = blockIdx.x >> 4;
    int tx = threadIdx.x & 31, ty = threadIdx.x >> 5;
#pragma unroll
    for (int i = 0; i < 32; i += 8)
        t[ty + i][tx] = f2bf(W[(by * 32 + ty + i) * 512 + bx * 32 + tx]);
    __syncthreads();
#pragma unroll
    for (int i = 0; i < 32; i += 8)
        WT[(bx * 32 + ty + i) * 512 + by * 32 + tx] = t[tx][ty + i];
}

// -------- kernel 2 (fused): blocks 0-511 = gemm (bf16 B path); 512-1535 = pack ------
__global__ __launch_bounds__(256, 4) void gemm_pack(const ushort_t* __restrict__ WT,
                                                    const ushort_t* __restrict__ hB,
                                                    const float* __restrict__ a,
                                                    ushort_t* __restrict__ WhT,
                                                    float* __restrict__ expA,
                                                    float* __restrict__ expC,
                                                    float* __restrict__ expB,
                                                    float* __restrict__ expD,
                                                    const int* __restrict__ adj,
                                                    unsigned char* __restrict__ pk) {
    __shared__ __align__(16) ushort_t Al[2][64][72];
    __shared__ __align__(16) ushort_t Bl[2][64][72];
    __shared__ float asrc[64], adst[64];
    __shared__ float sred[2][4][64];
    int tid = threadIdx.x;
    if (blockIdx.x >= 512) {
        // ---------------- pack branch ----------------
        int pbid = blockIdx.x - 512;
        int wv = tid >> 6, lane = tid & 63;
        int row = pbid * 4 + wv;
        const int* ap = adj + (unsigned)row * 4096 + lane;
        unsigned char* pp = pk + (unsigned)row * 512;
        int g = lane;                                 // lanes 0..15 write
        int sv = ((g >> 2) & 1) * 4 + (g & 3);
        int cpar = g >> 3;
#pragma unroll 2
        for (int t = 0; t < 8; t++) {
            unsigned long long m[8];
#pragma unroll
            for (int c8 = 0; c8 < 8; c8++)
                m[c8] = __ballot(ap[(t * 8 + c8) * 64] > 0);
            if (lane < 16) {
                unsigned w = 0;
#pragma unroll
                for (int kq = 0; kq < 4; kq++) {
                    unsigned b = (unsigned)(m[2 * kq + cpar] >> (8 * sv)) & 0xFFu;
                    w |= b << (8 * kq);
                }
                *(unsigned*)(pp + g * 32 + t * 4) = w;
            }
        }
        return;
    }
    // ---------------- gemm branch (r8/r12 proven, bf16 B) ----------------
    int wave = tid >> 6, lane = tid & 63, quad = lane >> 4, nn = lane & 15;
    int mb = blockIdx.x & 7, nb = blockIdx.x >> 3;
    if (tid < 64) {
        asrc[tid] = a[tid] * LOG2E;
        adst[tid] = a[64 + tid] * LOG2E;
    }
    int r = tid >> 2, s0 = tid & 3;
    const ushort_t* Ag = WT + (unsigned)((mb * 64 + r) * 512 + s0 * 8);
    const ushort_t* Bg = hB + (unsigned)((nb * 64 + r) * 512 + s0 * 8);
    bf16x8 pA0 = *(const bf16x8*)(Ag);
    bf16x8 pA1 = *(const bf16x8*)(Ag + 32);
    bf16x8 pB0 = *(const bf16x8*)(Bg);
    bf16x8 pB1 = *(const bf16x8*)(Bg + 32);
    f32x4 acc[4] = {};
#pragma unroll 2
    for (int t = 0; t < 8; t++) {
        int cb = t & 1;
        *(bf16x8*)&Al[cb][r][s0 * 8] = pA0;
        *(bf16x8*)&Al[cb][r][s0 * 8 + 32] = pA1;
        *(bf16x8*)&Bl[cb][r][s0 * 8] = pB0;
        *(bf16x8*)&Bl[cb][r][s0 * 8 + 32] = pB1;
        if (t < 7) {
            int ko = (t + 1) * 64;
            pA0 = *(const bf16x8*)(Ag + ko);
            pA1 = *(const bf16x8*)(Ag + ko + 32);
            pB0 = *(const bf16x8*)(Bg + ko);
            pB1 = *(const bf16x8*)(Bg + ko + 32);
        }
        if (t > 0) {
            int pb = cb ^ 1;
            bf16x8 af0 = *(const bf16x8*)&Al[pb][wave * 16 + nn][quad * 8];
            bf16x8 af1 = *(const bf16x8*)&Al[pb][wave * 16 + nn][32 + quad * 8];
#pragma unroll
            for (int nt = 0; nt < 4; nt++) {
                bf16x8 b0 = *(const bf16x8*)&Bl[pb][nt * 16 + nn][quad * 8];
                bf16x8 b1 = *(const bf16x8*)&Bl[pb][nt * 16 + nn][32 + quad * 8];
                acc[nt] = __builtin_amdgcn_mfma_f32_16x16x32_bf16(af0, b0, acc[nt], 0, 0, 0);
                acc[nt] = __builtin_amdgcn_mfma_f32_16x16x32_bf16(af1, b1, acc[nt], 0, 0, 0);
            }
        }
        __syncthreads();
    }
    {
        bf16x8 af0 = *(const bf16x8*)&Al[1][wave * 16 + nn][quad * 8];
        bf16x8 af1 = *(const bf16x8*)&Al[1][wave * 16 + nn][32 + quad * 8];
#pragma unroll
        for (int nt = 0; nt < 4; nt++) {
            bf16x8 b0 = *(const bf16x8*)&Bl[1][nt * 16 + nn][quad * 8];
            bf16x8 b1 = *(const bf16x8*)&Bl[1][nt * 16 + nn][32 + quad * 8];
            acc[nt] = __builtin_amdgcn_mfma_f32_16x16x32_bf16(af0, b0, acc[nt], 0, 0, 0);
            acc[nt] = __builtin_amdgcn_mfma_f32_16x16x32_bf16(af1, b1, acc[nt], 0, 0, 0);
        }
    }
    int row0 = mb * 64 + wave * 16 + quad * 4;
    int col0 = nb * 64 + nn;
    int f0i = wave * 16 + quad * 4;
#pragma unroll
    for (int nt = 0; nt < 4; nt++) {
        float s = 0.f, d = 0.f;
#pragma unroll
        for (int rr = 0; rr < 4; rr++) {
            float v = acc[nt][rr];
            WhT[(unsigned)((row0 + rr) * 4096 + col0 + nt * 16)] = f2bf(v);
            s += v * asrc[f0i + rr];
            d += v * adst[f0i + rr];
        }
        s += __shfl_xor(s, 16); s += __shfl_xor(s, 32);
        d += __shfl_xor(d, 16); d += __shfl_xor(d, 32);
        if (quad == 0) { sred[0][wave][nt * 16 + nn] = s; sred[1][wave][nt * 16 + nn] = d; }
    }
    __syncthreads();
    if (tid < 64) {
        float s = sred[0][0][tid] + sred[0][1][tid] + sred[0][2][tid] + sred[0][3][tid];
        unsigned idx = mb * 4096 + nb * 64 + tid;
        expA[idx] = __builtin_amdgcn_exp2f(s);
        expC[idx] = __builtin_amdgcn_exp2f(0.2f * s);
    } else if (tid < 128) {
        int c = tid - 64;
        float d = sred[1][0][c] + sred[1][1][c] + sred[1][2][c] + sred[1][3][c];
        unsigned idx = mb * 4096 + nb * 64 + c;
        expB[idx] = __builtin_amdgcn_exp2f(d);
        expD[idx] = __builtin_amdgcn_exp2f(0.2f * d);
    }
}

// -------- kernel 3: fused attention, j-tile 128 (EXACT r13, 59.5us optimum) ---------
// 512 blocks x 512 thr (512,4). wave=(whead, jq); thread gen = A-frags for rows
// nn and 16+nn over j = kb*128 + jq*32 + quad*8 + 0..7. 32 iters, 1 barrier each.
__global__ __launch_bounds__(512, 4) void gat_attn(const unsigned char* __restrict__ pk,
                                                   const ushort_t* __restrict__ WhT,
                                                   const float* __restrict__ expA,
                                                   const float* __restrict__ expC,
                                                   const float* __restrict__ expB,
                                                   const float* __restrict__ expD,
                                                   float* __restrict__ out) {
    __shared__ __align__(16) ushort_t Vb[2][128][136];   // 69632 B (cmb overlays)
    __shared__ float denomp[4][2][32];
    int tid = threadIdx.x;
    int wave = tid >> 6, lane = tid & 63, quad = lane >> 4, nn = lane & 15;
    int hb = blockIdx.x >> 7, ib = blockIdx.x & 127;   // adj row-band on one XCD
    int i0 = ib * 32;
    int whead = wave & 1, jq = wave >> 1;              // jq 0..3
    int g = jq * 4 + quad;
    int head = hb * 2 + whead;
    float Ai0 = expA[head * 4096 + i0 + nn];
    float Ci0 = expC[head * 4096 + i0 + nn];
    float Ai1 = expA[head * 4096 + i0 + 16 + nn];
    float Ci1 = expC[head * 4096 + i0 + 16 + nn];
    const unsigned char* mpA = pk + (unsigned)(i0 + nn) * 512 + g * 32;
    const unsigned char* mpB = mpA + 16 * 512;
    const float* Bp = expB + (unsigned)head * 4096 + jq * 32 + quad * 8;
    const float* Dp = expD + (unsigned)head * 4096 + jq * 32 + quad * 8;
    // V staging: row vrow, 4 x 16B segs at cols vs*8 + s*32
    int vrow = tid >> 2, vs = tid & 3;
    const ushort_t* Vg = WhT + (unsigned)(hb * 128 + vrow) * 4096 + vs * 8;
    bf16x8 onef;
#pragma unroll
    for (int i = 0; i < 8; i++) onef[i] = (short)0x3F80;   // bf16 1.0
    f32x4 acc[2][4] = {};
    f32x4 accd[2] = {};
    bf16x8 pv[4];
    float4 pBD[4];
    pv[0] = *(const bf16x8*)(Vg);
    pv[1] = *(const bf16x8*)(Vg + 32);
    pv[2] = *(const bf16x8*)(Vg + 64);
    pv[3] = *(const bf16x8*)(Vg + 96);
    pBD[0] = *(const float4*)(Bp);
    pBD[1] = *(const float4*)(Bp + 4);
    pBD[2] = *(const float4*)(Dp);
    pBD[3] = *(const float4*)(Dp + 4);
    unsigned mcA = *(const unsigned*)(mpA);
    unsigned mcB = *(const unsigned*)(mpB);
    unsigned mnA = 0, mnB = 0;
    for (int t = 0; t < 8; t++) {
#pragma unroll
        for (int u = 0; u < 4; u++) {
            int kb = t * 4 + u;
            int cb = kb & 1;
            // ---- store V tile kb ----
            *(bf16x8*)&Vb[cb][vrow][vs * 8] = pv[0];
            *(bf16x8*)&Vb[cb][vrow][vs * 8 + 32] = pv[1];
            *(bf16x8*)&Vb[cb][vrow][vs * 8 + 64] = pv[2];
            *(bf16x8*)&Vb[cb][vrow][vs * 8 + 96] = pv[3];
            // ---- gen both strips (shared B/D) ----
            float4 Bv0 = pBD[0], Bv1 = pBD[1], Dv0 = pBD[2], Dv1 = pBD[3];
            bf16x8 af0, af1;
            {
                unsigned w0, w1, w2, w3, w4, w5, w6, w7;
                float w;
                w = fmaxf(Ai0 * Bv0.x, Ci0 * Dv0.x);
                w0 = __builtin_bit_cast(unsigned, w) & 0xFFFF0000u;
                w0 &= (unsigned)__builtin_amdgcn_sbfe(mcA, u * 8 + 0, 1);
                w = fmaxf(Ai0 * Bv0.y, Ci0 * Dv0.y);
                w1 = __builtin_bit_cast(unsigned, w) & 0xFFFF0000u;
                w1 &= (unsigned)__builtin_amdgcn_sbfe(mcA, u * 8 + 1, 1);
                w = fmaxf(Ai0 * Bv0.z, Ci0 * Dv0.z);
                w2 = __builtin_bit_cast(unsigned, w) & 0xFFFF0000u;
                w2 &= (unsigned)__builtin_amdgcn_sbfe(mcA, u * 8 + 2, 1);
                w = fmaxf(Ai0 * Bv0.w, Ci0 * Dv0.w);
                w3 = __builtin_bit_cast(unsigned, w) & 0xFFFF0000u;
                w3 &= (unsigned)__builtin_amdgcn_sbfe(mcA, u * 8 + 3, 1);
                w = fmaxf(Ai0 * Bv1.x, Ci0 * Dv1.x);
                w4 = __builtin_bit_cast(unsigned, w) & 0xFFFF0000u;
                w4 &= (unsigned)__builtin_amdgcn_sbfe(mcA, u * 8 + 4, 1);
                w = fmaxf(Ai0 * Bv1.y, Ci0 * Dv1.y);
                w5 = __builtin_bit_cast(unsigned, w) & 0xFFFF0000u;
                w5 &= (unsigned)__builtin_amdgcn_sbfe(mcA, u * 8 + 5, 1);
                w = fmaxf(Ai0 * Bv1.z, Ci0 * Dv1.z);
                w6 = __builtin_bit_cast(unsigned, w) & 0xFFFF0000u;
                w6 &= (unsigned)__builtin_amdgcn_sbfe(mcA, u * 8 + 6, 1);
                w = fmaxf(Ai0 * Bv1.w, Ci0 * Dv1.w);
                w7 = __builtin_bit_cast(unsigned, w) & 0xFFFF0000u;
                w7 &= (unsigned)__builtin_amdgcn_sbfe(mcA, u * 8 + 7, 1);
                uint4 pq;
                pq.x = __builtin_amdgcn_perm(w1, w0, 0x07060302u);
                pq.y = __builtin_amdgcn_perm(w3, w2, 0x07060302u);
                pq.z = __builtin_amdgcn_perm(w5, w4, 0x07060302u);
                pq.w = __builtin_amdgcn_perm(w7, w6, 0x07060302u);
                af0 = __builtin_bit_cast(bf16x8, pq);
                w = fmaxf(Ai1 * Bv0.x, Ci1 * Dv0.x);
                w0 = __builtin_bit_cast(unsigned, w) & 0xFFFF0000u;
                w0 &= (unsigned)__builtin_amdgcn_sbfe(mcB, u * 8 + 0, 1);
                w = fmaxf(Ai1 * Bv0.y, Ci1 * Dv0.y);
                w1 = __builtin_bit_cast(unsigned, w) & 0xFFFF0000u;
                w1 &= (unsigned)__builtin_amdgcn_sbfe(mcB, u * 8 + 1, 1);
                w = fmaxf(Ai1 * Bv0.z, Ci1 * Dv0.z);
                w2 = __builtin_bit_cast(unsigned, w) & 0xFFFF0000u;
                w2 &= (unsigned)__builtin_amdgcn_sbfe(mcB, u * 8 + 2, 1);
                w = fmaxf(Ai1 * Bv0.w, Ci1 * Dv0.w);
                w3 = __builtin_bit_cast(unsigned, w) & 0xFFFF0000u;
                w3 &= (unsigned)__builtin_amdgcn_sbfe(mcB, u * 8 + 3, 1);
                w = fmaxf(Ai1 * Bv1.x, Ci1 * Dv1.x);
                w4 = __builtin_bit_cast(unsigned, w) & 0xFFFF0000u;
                w4 &= (unsigned)__builtin_amdgcn_sbfe(mcB, u * 8 + 4, 1);
                w = fmaxf(Ai1 * Bv1.y, Ci1 * Dv1.y);
                w5 = __builtin_bit_cast(unsigned, w) & 0xFFFF0000u;
                w5 &= (unsigned)__builtin_amdgcn_sbfe(mcB, u * 8 + 5, 1);
                w = fmaxf(Ai1 * Bv1.z, Ci1 * Dv1.z);
                w6 = __builtin_bit_cast(unsigned, w) & 0xFFFF0000u;
                w6 &= (unsigned)__builtin_amdgcn_sbfe(mcB, u * 8 + 6, 1);
                w = fmaxf(Ai1 * Bv1.w, Ci1 * Dv1.w);
                w7 = __builtin_bit_cast(unsigned, w) & 0xFFFF0000u;
                w7 &= (unsigned)__builtin_amdgcn_sbfe(mcB, u * 8 + 7, 1);
                pq.x = __builtin_amdgcn_perm(w1, w0, 0x07060302u);
                pq.y = __builtin_amdgcn_perm(w3, w2, 0x07060302u);
                pq.z = __builtin_amdgcn_perm(w5, w4, 0x07060302u);
                pq.w = __builtin_amdgcn_perm(w7, w6, 0x07060302u);
                af1 = __builtin_bit_cast(bf16x8, pq);
            }
            if (u == 3) { mcA = mnA; mcB = mnB; }
            __syncthreads();                       // drains only iter-old loads
            __builtin_amdgcn_sched_barrier(0);     // pin: loads below stay below
            // ---- prefetch tile kb+1 ----
            if (kb < 31) {
                const ushort_t* vp = Vg + (kb + 1) * 128;
                pv[0] = *(const bf16x8*)(vp);
                pv[1] = *(const bf16x8*)(vp + 32);
                pv[2] = *(const bf16x8*)(vp + 64);
                pv[3] = *(const bf16x8*)(vp + 96);
                pBD[0] = *(const float4*)(Bp + (kb + 1) * 128);
                pBD[1] = *(const float4*)(Bp + (kb + 1) * 128 + 4);
                pBD[2] = *(const float4*)(Dp + (kb + 1) * 128);
                pBD[3] = *(const float4*)(Dp + (kb + 1) * 128 + 4);
            }
            if (u == 0 && t < 7) {
                mnA = *(const unsigned*)(mpA + (t + 1) * 4);
                mnB = *(const unsigned*)(mpB + (t + 1) * 4);
            }
            // ---- MFMA tile kb: each bv feeds both strips ----
#pragma unroll
            for (int nt = 0; nt < 4; nt++) {
                bf16x8 bv = *(const bf16x8*)&Vb[cb][whead * 64 + nt * 16 + nn][jq * 32 + quad * 8];
                acc[0][nt] = __builtin_amdgcn_mfma_f32_16x16x32_bf16(af0, bv, acc[0][nt], 0, 0, 0);
                acc[1][nt] = __builtin_amdgcn_mfma_f32_16x16x32_bf16(af1, bv, acc[1][nt], 0, 0, 0);
            }
            accd[0] = __builtin_amdgcn_mfma_f32_16x16x32_bf16(af0, onef, accd[0], 0, 0, 0);
            accd[1] = __builtin_amdgcn_mfma_f32_16x16x32_bf16(af1, onef, accd[1], 0, 0, 0);
        }
    }
    __syncthreads();   // all Vb reads of tile 31 done before cmb overlay writes
    // denominator partials: row = s*16 + quad*4 + rr
    if (nn == 0) {
#pragma unroll
        for (int s = 0; s < 2; s++)
#pragma unroll
            for (int rr = 0; rr < 4; rr++)
                denomp[jq][whead][s * 16 + quad * 4 + rr] = accd[s][rr];
    }
    // combine jq partials via cmb overlay on Vb
    float (*cmb)[3][64][32] = reinterpret_cast<float (*)[3][64][32]>(&Vb[0][0][0]);
    if (jq > 0) {
#pragma unroll
        for (int s = 0; s < 2; s++)
#pragma unroll
            for (int nt = 0; nt < 4; nt++)
                *(f32x4*)&cmb[whead][jq - 1][lane][s * 16 + nt * 4] = acc[s][nt];
    }
    __syncthreads();
    if (jq == 0) {
#pragma unroll
        for (int s = 0; s < 2; s++) {
#pragma unroll
            for (int nt = 0; nt < 4; nt++) {
                f32x4 o = acc[s][nt]
                        + *(const f32x4*)&cmb[whead][0][lane][s * 16 + nt * 4]
                        + *(const f32x4*)&cmb[whead][1][lane][s * 16 + nt * 4]
                        + *(const f32x4*)&cmb[whead][2][lane][s * 16 + nt * 4];
#pragma unroll
                for (int rr = 0; rr < 4; rr++) {
                    int il = s * 16 + quad * 4 + rr;
                    float dnm = fmaxf(denomp[0][whead][il] + denomp[1][whead][il]
                                    + denomp[2][whead][il] + denomp[3][whead][il], 1e-30f);
                    float v = o[rr] / dnm;
                    v = v > 0.f ? v : __expf(v) - 1.f;
                    out[(unsigned)(i0 + il) * 512 + hb * 128 + whead * 64 + nt * 16 + nn] = v;
                }
            }
        }
    }
}

extern "C" void kernel_launch(void* const* d_in, const int* in_sizes, int n_in,
                              void* d_out, int out_size, void* d_ws, size_t ws_size,
                              hipStream_t stream) {
    const float* h   = (const float*)d_in[0];   // 4096 x 512 fp32
    const int*   adj = (const int*)d_in[1];     // 4096 x 4096 int32
    const float* W   = (const float*)d_in[2];   // 512 x 512 fp32
    const float* a   = (const float*)d_in[3];   // 128 fp32

    char* ws = (char*)d_ws;
    ushort_t* WhT = (ushort_t*)ws;                           // 4 MB
    ushort_t* WT  = (ushort_t*)(ws + (4u << 20));            // 512 KB
    float* expA = (float*)(ws + (4u << 20) + (512u << 10));  // 4 x 128 KB
    float* expC = expA + 8 * 4096;
    float* expB = expC + 8 * 4096;
    float* expD = expB + 8 * 4096;
    unsigned char* pkm = (unsigned char*)(ws + (5u << 20));  // 2 MB bitmask
    ushort_t* hB = (ushort_t*)(ws + (7u << 20));             // 4 MB bf16 h

    transpose_w<<<768, 256, 0, stream>>>(W, WT, h, hB);
    gemm_pack<<<1536, 256, 0, stream>>>(WT, hB, a, WhT, expA, expC, expB, expD,
                                        adj, pkm);
    gat_attn<<<512, 512, 0, stream>>>(pkm, WhT, expA, expC, expB, expD,
                                      (float*)d_out);
}